// Round 19
// baseline (1175.171 us; speedup 1.0000x reference)
//
#include <hip/hip_runtime.h>
#include <hip/hip_bf16.h>

typedef __hip_bfloat16 bf16;
typedef __attribute__((ext_vector_type(8))) short bf16x8;   // 8 bf16 (4 VGPRs)
typedef __attribute__((ext_vector_type(4))) float f32x4;    // 4 fp32 acc
#define DEV static __device__ __forceinline__

DEV float b2f(bf16 v) { return __bfloat162float(v); }
DEV bf16  f2b(float v) { return __float2bfloat16(v); }
DEV unsigned short f2u(float v) { bf16 t = f2b(v); return *(unsigned short*)&t; }
DEV float u2f(unsigned short u) { bf16 t = *(bf16*)&u; return __bfloat162float(t); }
DEV float sigf(float x) { return 1.0f / (1.0f + __expf(-x)); }
DEV float tanhfast(float x) { return 2.0f / (1.0f + __expf(-2.0f * x)) - 1.0f; }

// ---------------------------------------------------------------------------
// fp32 I/O (proved r4). Round-19: REVERT to round 17 verbatim (1174.8 us,
// passed) after the cooperative-LSTM experiment (r18) failed correctness.
// Per-kernel best-of: dec1 naive single-buffer; pw r14 LDS double-buffer;
// conv2/conv3/dec2f W-pipelined; conv1 MFMA parity-pool; merged canon/prep.
// ws layout unchanged (end 61.6 MB <= 63.95 MB confirmed).
// ---------------------------------------------------------------------------

__global__ void k_detect(const unsigned short* __restrict__ xb, int nscan, int* flag)
{
    __shared__ int cnt_s[256];
    int tid = threadIdx.x;
    int c = 0;
    for (int i = tid; i < nscan; i += 256) {
        unsigned int e = (xb[i] >> 7) & 0xFF;
        c += (e >= 0xC0);
    }
    cnt_s[tid] = c;
    __syncthreads();
    for (int off = 128; off > 0; off >>= 1) {
        if (tid < off) cnt_s[tid] += cnt_s[tid + off];
        __syncthreads();
    }
    if (tid == 0) *flag = (cnt_s[0] > 256) ? 1 : 0;
}

struct CanonSrc { const void* s[15]; };

__global__ __launch_bounds__(256) void k_canon_all(
    CanonSrc cs, char* __restrict__ wsb, int total, const int* __restrict__ flag)
{
    static const __device__ int off_d[16] = {0, 1728, 1792, 75520, 75648, 370560,
        370816, 375424, 899712, 900736, 1195648, 1195776, 1269504, 1269568,
        1269632, 1269633};
    static const __device__ long woff_d[15] = {0, 3456, 3584, 151040, 151296,
        741120, 741632, 750848, 1799424, 1801472, 2391296, 2391552, 2539008,
        2539136, 2539264};
    int i = blockIdx.x * 256 + threadIdx.x;
    if (i >= total) return;
    int t = 0;
    while (t < 14 && i >= off_d[t + 1]) ++t;
    int j = i - off_d[t];
    bf16* dst = (bf16*)(wsb + woff_d[t]);
    if (*flag) dst[j] = f2b(((const float*)cs.s[t])[j]);
    else       dst[j] = ((const bf16*)cs.s[t])[j];
}

__global__ __launch_bounds__(256) void k_prep_all(char* __restrict__ wsb)
{
    long gid = (long)blockIdx.x * 256 + threadIdx.x;
    if (gid < 524288) {
        int idx = (int)gid;
        const bf16* w = (const bf16*)(wsb + 1801472);
        bf16* wc1 = (bf16*)(wsb + 2539296);
        int ci = idx & 255, tap = (idx >> 8) & 3;
        int oc = (idx >> 10) & 127, par = idx >> 17;
        int a = tap >> 1, b = tap & 1;
        int py = par >> 1, px = par & 1;
        const bf16* wb = w + (oc * 256 + ci) * 9;
        float v = 0.f;
        #pragma unroll
        for (int ky = 0; ky < 3; ++ky) {
            bool rok = (py == 0) ? (a == 0 ? (ky == 0) : (ky >= 1))
                                 : (a == 0 ? (ky <= 1) : (ky == 2));
            if (!rok) continue;
            #pragma unroll
            for (int kx = 0; kx < 3; ++kx) {
                bool cok = (px == 0) ? (b == 0 ? (kx == 0) : (kx >= 1))
                                     : (b == 0 ? (kx <= 1) : (kx == 2));
                if (cok) v += b2f(wb[ky * 3 + kx]);
            }
        }
        wc1[idx] = f2b(v);
    } else if (gid < 655360) {
        int idx = (int)(gid - 524288);
        const bf16* w = (const bf16*)(wsb + 2391552);
        bf16* wc2 = (bf16*)(wsb + 3587872);
        int ci = idx & 127, tap = (idx >> 7) & 3;
        int oc = (idx >> 9) & 63, par = idx >> 15;
        int a = tap >> 1, b = tap & 1;
        int py = par >> 1, px = par & 1;
        const bf16* wb = w + (oc * 128 + ci) * 9;
        float v = 0.f;
        #pragma unroll
        for (int ky = 0; ky < 3; ++ky) {
            bool rok = (py == 0) ? (a == 0 ? (ky == 0) : (ky >= 1))
                                 : (a == 0 ? (ky <= 1) : (ky == 2));
            if (!rok) continue;
            #pragma unroll
            for (int kx = 0; kx < 3; ++kx) {
                bool cok = (px == 0) ? (b == 0 ? (kx == 0) : (kx >= 1))
                                     : (b == 0 ? (kx <= 1) : (kx == 2));
                if (cok) v += b2f(wb[ky * 3 + kx]);
            }
        }
        wc2[idx] = f2b(v);
    } else if (gid < 1179648) {
        int idx = (int)(gid - 655360);
        const bf16* pww = (const bf16*)(wsb + 750848);
        bf16* wcp = (bf16*)(wsb + 3850016);
        int k = idx & 511, m = idx >> 9;
        int ch = m >> 2, gate = m & 3;
        wcp[idx] = pww[(gate * 256 + ch) * 512 + k];
    } else if (gid < 1474560) {
        int idx = (int)(gid - 1179648);
        const bf16* w = (const bf16*)(wsb + 151296);
        bf16* wc3 = (bf16*)(wsb + 4898592);
        int oc = idx / 1152, rem = idx % 1152;
        int tap = rem >> 7, ci = rem & 127;
        wc3[idx] = w[(oc * 128 + ci) * 9 + tap];
    } else if (gid < 1548288) {
        int idx = (int)(gid - 1474560);
        const bf16* w = (const bf16*)(wsb + 3584);
        bf16* wc2e = (bf16*)(wsb + 5488416);
        int oc = idx / 576, rem = idx % 576;
        int tap = rem >> 6, ci = rem & 63;
        wc2e[idx] = w[(oc * 64 + ci) * 9 + tap];
    } else if (gid < 1550336) {
        int idx = (int)(gid - 1548288);
        const bf16* w = (const bf16*)(wsb + 0);
        bf16* wc1e = (bf16*)(wsb + 5635872);
        int oc = idx >> 5, k = idx & 31;
        bf16 v = f2b(0.f);
        if (k < 27) v = w[oc * 27 + k];
        wc1e[idx] = v;
    } else if (gid < 1554944) {
        int idx = (int)(gid - 1550336);
        const bf16* w = (const bf16*)(wsb + 741632);
        bf16* dwt = (bf16*)(wsb + 5639968);
        int tap = idx >> 9, ch = idx & 511;
        dwt[idx] = w[ch * 9 + tap];
    }
}

// K1: conv 3->64 + relu + pool via MFMA, parity-fused.
__global__ __launch_bounds__(256) void k_conv1_mfma(
    const void* __restrict__ xv, const bf16* __restrict__ wc1e,
    const bf16* __restrict__ bias, bf16* __restrict__ p1c, int fbase,
    const int* __restrict__ flag)
{
    __shared__ __align__(16) short W_s[64 * 40];
    __shared__ __align__(16) short H_s[3 * 6 * 88];
    const int nt = blockIdx.x, z = blockIdx.z;
    const int n = fbase + z;
    const int tid = threadIdx.x;
    const int wave = tid >> 6, lane = tid & 63;
    const int quad = lane >> 4, nl = lane & 15;
    const int nn = wave * 16 + nl;
    const int p0 = nt * 63, y0 = p0 / 42;
    const int np = p0 + ((nn < 63) ? nn : 62);
    const int y = np / 42, xq = np % 42;
    const int isf32 = *flag;
    for (int u = tid; u < 256; u += 256) {
        int m = u >> 2, k8 = (u & 3) * 8;
        *(uint4*)&W_s[m * 40 + k8] = *(const uint4*)&wc1e[m * 32 + k8];
    }
    for (int i = tid; i < 1548; i += 256) {
        int ci = i / 516, rem = i % 516, r = rem / 86, col = rem % 86;
        int gy = 2 * y0 - 1 + r, gx = col - 1;
        float v = 0.f;
        if (gy >= 0 && gy < 84 && gx >= 0 && gx < 84) {
            int idx = (n * 3 + ci) * 7056 + gy * 84 + gx;
            v = isf32 ? ((const float*)xv)[idx] : b2f(((const bf16*)xv)[idx]);
        }
        H_s[(ci * 6 + r) * 88 + col] = f2u(v);
    }
    __syncthreads();
    bf16x8 af[4];
    #pragma unroll
    for (int f = 0; f < 4; ++f)
        af[f] = *(const bf16x8*)&W_s[(f * 16 + nl) * 40 + quad * 8];
    f32x4 acc[4][4];
    #pragma unroll
    for (int p = 0; p < 4; ++p)
        #pragma unroll
        for (int f = 0; f < 4; ++f) acc[p][f] = (f32x4){0.f, 0.f, 0.f, 0.f};
    const int yl = y - y0;
    #pragma unroll
    for (int par = 0; par < 4; ++par) {
        const int pa = par >> 1, pb = par & 1;
        bf16x8 bv;
        #pragma unroll
        for (int j = 0; j < 8; ++j) {
            int k = quad * 8 + j;
            short v = 0;
            if (k < 27) {
                int ci = k / 9, tap = k % 9;
                int dy = tap / 3, dx = tap % 3;
                v = H_s[(ci * 6 + 2 * yl + pa + dy) * 88 + 2 * xq + pb + dx];
            }
            bv[j] = v;
        }
        #pragma unroll
        for (int f = 0; f < 4; ++f)
            acc[par][f] = __builtin_amdgcn_mfma_f32_16x16x32_bf16(
                af[f], bv, acc[par][f], 0, 0, 0);
    }
    if (nn < 63) {
        #pragma unroll
        for (int f = 0; f < 4; ++f) {
            ushort4 o;
            unsigned short* op = (unsigned short*)&o;
            #pragma unroll
            for (int reg = 0; reg < 4; ++reg) {
                const int oc = f * 16 + quad * 4 + reg;
                float m = fmaxf(fmaxf(acc[0][f][reg], acc[1][f][reg]),
                                fmaxf(acc[2][f][reg], acc[3][f][reg]));
                op[reg] = f2u(fmaxf(m + b2f(bias[oc]), 0.f));
            }
            *(ushort4*)&p1c[((long)z * 1764 + np) * 64 + f * 16 + quad * 4] = o;
        }
    }
}

// K2: conv 64->128 + relu + maxpool via MFMA, parity-fused, W-pipelined (r14).
__global__ __launch_bounds__(256) void k_conv2_mfma(
    const bf16* __restrict__ p1c, const bf16* __restrict__ wc2e,
    const bf16* __restrict__ bias, bf16* __restrict__ p2c)
{
    __shared__ __align__(16) short H_s[352 * 72];
    __shared__ __align__(16) short W_s[2][128 * 40];
    const int nt = blockIdx.x, z = blockIdx.z;
    const int tid = threadIdx.x;
    const int wave = tid >> 6, lane = tid & 63;
    const int quad = lane >> 4, nl = lane & 15;
    const int nn = wave * 16 + nl;
    const int np = (nn < 63) ? nn : 62;
    const int iyl = np / 21, ix = np % 21;
    const int r0 = nt * 3;
    for (int u = tid; u < 2816; u += 256) {
        int rc = u >> 3, c8 = u & 7;
        int gy = 2 * r0 - 1 + rc / 44, gx = (rc % 44) - 1;
        uint4 v = {0, 0, 0, 0};
        if (gy >= 0 && gy < 42 && gx >= 0 && gx < 42)
            v = *(const uint4*)&p1c[((long)z * 1764 + gy * 42 + gx) * 64 + c8 * 8];
        *(uint4*)&H_s[rc * 72 + c8 * 8] = v;
    }
    const int m0 = tid >> 2, k80 = (tid & 3) * 8;
    const int m1 = (tid + 256) >> 2, k81 = ((tid + 256) & 3) * 8;
    *(uint4*)&W_s[0][m0 * 40 + k80] = *(const uint4*)&wc2e[m0 * 576 + k80];
    *(uint4*)&W_s[0][m1 * 40 + k81] = *(const uint4*)&wc2e[m1 * 576 + k81];
    __syncthreads();
    f32x4 acc[4][8];
    #pragma unroll
    for (int p = 0; p < 4; ++p)
        #pragma unroll
        for (int f = 0; f < 8; ++f) acc[p][f] = (f32x4){0.f, 0.f, 0.f, 0.f};
    for (int it = 0; it < 18; ++it) {
        const int tap = it >> 1, cc = it & 1;
        const bool ld = (it + 1 < 18);
        uint4 wr0, wr1;
        if (ld) {
            const int ntap = (it + 1) >> 1, ncc = (it + 1) & 1;
            const bf16* src = wc2e + ntap * 64 + ncc * 32;
            wr0 = *(const uint4*)&src[m0 * 576 + k80];
            wr1 = *(const uint4*)&src[m1 * 576 + k81];
        }
        const int dy = tap / 3, dx = tap % 3;
        const short* Wc = W_s[it & 1];
        bf16x8 af[8];
        #pragma unroll
        for (int f = 0; f < 8; ++f)
            af[f] = *(const bf16x8*)&Wc[(f * 16 + nl) * 40 + quad * 8];
        #pragma unroll
        for (int par = 0; par < 4; ++par) {
            const int pa = par >> 1, pb = par & 1;
            const int hy = 2 * iyl + pa + dy;
            const int hx = 2 * ix + pb + dx;
            const bf16x8 bv =
                *(const bf16x8*)&H_s[(hy * 44 + hx) * 72 + cc * 32 + quad * 8];
            #pragma unroll
            for (int f = 0; f < 8; ++f)
                acc[par][f] = __builtin_amdgcn_mfma_f32_16x16x32_bf16(
                    af[f], bv, acc[par][f], 0, 0, 0);
        }
        if (ld) {
            short* Wn = W_s[(it + 1) & 1];
            *(uint4*)&Wn[m0 * 40 + k80] = wr0;
            *(uint4*)&Wn[m1 * 40 + k81] = wr1;
        }
        __syncthreads();
    }
    if (nn < 63) {
        #pragma unroll
        for (int f = 0; f < 8; ++f) {
            ushort4 o;
            unsigned short* op = (unsigned short*)&o;
            #pragma unroll
            for (int reg = 0; reg < 4; ++reg) {
                const int oc = f * 16 + quad * 4 + reg;
                float m = fmaxf(fmaxf(acc[0][f][reg], acc[1][f][reg]),
                                fmaxf(acc[2][f][reg], acc[3][f][reg]));
                op[reg] = f2u(fmaxf(m + b2f(bias[oc]), 0.f));
            }
            *(ushort4*)&p2c[((long)z * 441 + (r0 + iyl) * 21 + ix) * 128 +
                            f * 16 + quad * 4] = o;
        }
    }
}

// K3: conv 128->256 + relu via MFMA, W-pipelined (r14). grid (7,2,64).
__global__ __launch_bounds__(256) void k_conv3_mfma(
    const bf16* __restrict__ p2c, const bf16* __restrict__ wc3,
    const bf16* __restrict__ bias, bf16* __restrict__ feats, int fbase)
{
    __shared__ __align__(16) short H_s[115 * 136];
    __shared__ __align__(16) short W_s[2][128 * 40];
    const int nt = blockIdx.x, oq = blockIdx.y, z = blockIdx.z;
    const int n = fbase + z;
    const int slot = (n & 15) * 8 + (n >> 4);
    const int tid = threadIdx.x;
    const int wave = tid >> 6, lane = tid & 63;
    const int quad = lane >> 4, nl = lane & 15;
    const int nn = wave * 16 + nl;
    const int np = (nn < 63) ? nn : 62;
    const int iyl = np / 21, ox = np % 21;
    const int r0 = nt * 3;
    for (int u = tid; u < 1840; u += 256) {
        int rc = u >> 4, c8 = u & 15;
        int gy = r0 + rc / 23 - 1, gx = (rc % 23) - 1;
        uint4 v = {0, 0, 0, 0};
        if (gy >= 0 && gy < 21 && gx >= 0 && gx < 21)
            v = *(const uint4*)&p2c[((long)z * 441 + gy * 21 + gx) * 128 + c8 * 8];
        *(uint4*)&H_s[rc * 136 + c8 * 8] = v;
    }
    const bf16* wbase = wc3 + (long)(oq * 128) * 1152;
    const int m0 = tid >> 2, k80 = (tid & 3) * 8;
    const int m1 = (tid + 256) >> 2, k81 = ((tid + 256) & 3) * 8;
    *(uint4*)&W_s[0][m0 * 40 + k80] = *(const uint4*)&wbase[m0 * 1152 + k80];
    *(uint4*)&W_s[0][m1 * 40 + k81] = *(const uint4*)&wbase[m1 * 1152 + k81];
    __syncthreads();
    f32x4 acc[8];
    #pragma unroll
    for (int f = 0; f < 8; ++f) acc[f] = (f32x4){0.f, 0.f, 0.f, 0.f};
    const int hb = iyl * 23 + ox;
    for (int it = 0; it < 36; ++it) {
        const int tap = it >> 2, cc = it & 3;
        const bool ld = (it + 1 < 36);
        uint4 wr0, wr1;
        if (ld) {
            const int ntap = (it + 1) >> 2, ncc = (it + 1) & 3;
            const bf16* src = wbase + ntap * 128 + ncc * 32;
            wr0 = *(const uint4*)&src[m0 * 1152 + k80];
            wr1 = *(const uint4*)&src[m1 * 1152 + k81];
        }
        const int dy = tap / 3, dx = tap % 3;
        const int hofs = (hb + dy * 23 + dx) * 136;
        const bf16x8 bv = *(const bf16x8*)&H_s[hofs + cc * 32 + quad * 8];
        const short* Wc = W_s[it & 1];
        #pragma unroll
        for (int f = 0; f < 8; ++f) {
            bf16x8 af = *(const bf16x8*)&Wc[(f * 16 + nl) * 40 + quad * 8];
            acc[f] = __builtin_amdgcn_mfma_f32_16x16x32_bf16(af, bv, acc[f], 0, 0, 0);
        }
        if (ld) {
            short* Wn = W_s[(it + 1) & 1];
            *(uint4*)&Wn[m0 * 40 + k80] = wr0;
            *(uint4*)&Wn[m1 * 40 + k81] = wr1;
        }
        __syncthreads();
    }
    if (nn < 63) {
        const int oy = r0 + iyl;
        #pragma unroll
        for (int f = 0; f < 8; ++f) {
            ushort4 o;
            unsigned short* op = (unsigned short*)&o;
            #pragma unroll
            for (int reg = 0; reg < 4; ++reg) {
                const int oc = oq * 128 + f * 16 + quad * 4 + reg;
                op[reg] = f2u(fmaxf(acc[f][reg] + b2f(bias[oc]), 0.f));
            }
            *(ushort4*)&feats[((long)slot * 441 + oy * 21 + ox) * 256 +
                              oq * 128 + f * 16 + quad * 4] = o;
        }
    }
}

// K4: depthwise 3x3, vectorized 8ch/thread -> dwout[b][441][512] bf16.
__global__ __launch_bounds__(256) void k_dw_vec(
    const bf16* __restrict__ feats, const float* __restrict__ h,
    const bf16* __restrict__ dwt, bf16* __restrict__ dwout, int t)
{
    int idx = blockIdx.x * 256 + threadIdx.x;
    if (idx >= 8 * 441 * 64) return;
    const int cg = idx & 63;
    const int p = (idx >> 6) % 441;
    const int b = idx / (441 * 64);
    const int ch = cg * 8;
    const int y = p / 21, x = p % 21;
    const bf16* fslot = feats + (long)(t * 8 + b) * 112896;
    const float* hb_ = h + (long)b * 112896;
    float a8[8];
    #pragma unroll
    for (int j = 0; j < 8; ++j) a8[j] = 0.f;
    #pragma unroll
    for (int ky = 0; ky < 3; ++ky) {
        int ny = y + ky - 1;
        if (ny < 0 || ny >= 21) continue;
        #pragma unroll
        for (int kx = 0; kx < 3; ++kx) {
            int nx = x + kx - 1;
            if (nx < 0 || nx >= 21) continue;
            const int tap = ky * 3 + kx;
            const bf16x8 wv = *(const bf16x8*)&dwt[tap * 512 + ch];
            if (ch < 256) {
                const bf16x8 xv = *(const bf16x8*)&fslot[(ny * 21 + nx) * 256 + ch];
                #pragma unroll
                for (int j = 0; j < 8; ++j)
                    a8[j] += u2f(((unsigned short*)&wv)[j]) *
                             u2f(((unsigned short*)&xv)[j]);
            } else {
                const float4 x0 = *(const float4*)&hb_[(ny * 21 + nx) * 256 + ch - 256];
                const float4 x1 = *(const float4*)&hb_[(ny * 21 + nx) * 256 + ch - 252];
                const float xf[8] = {x0.x, x0.y, x0.z, x0.w, x1.x, x1.y, x1.z, x1.w};
                #pragma unroll
                for (int j = 0; j < 8; ++j)
                    a8[j] += u2f(((unsigned short*)&wv)[j]) * xf[j];
            }
        }
    }
    ushort4 o0, o1;
    #pragma unroll
    for (int j = 0; j < 4; ++j) {
        ((unsigned short*)&o0)[j] = f2u(a8[j]);
        ((unsigned short*)&o1)[j] = f2u(a8[4 + j]);
    }
    *(ushort4*)&dwout[((long)b * 441 + p) * 512 + ch] = o0;
    *(ushort4*)&dwout[((long)b * 441 + p) * 512 + ch + 4] = o1;
}

// K5: pointwise + gates via MFMA, W/X LDS double-buffer 1-barrier (r14).
__global__ __launch_bounds__(256) void k_pw_mfma(
    const bf16* __restrict__ dwout, const bf16* __restrict__ wcp,
    const bf16* __restrict__ pwb, float* __restrict__ h, float* __restrict__ c,
    bf16* __restrict__ hst)
{
    __shared__ __align__(16) short W_s[2][128 * 72];
    __shared__ __align__(16) short X_s[2][64 * 72];
    __shared__ bf16 pb_s[1024];
    const int nt = blockIdx.x, mq = blockIdx.y, b = blockIdx.z;
    const int tid = threadIdx.x;
    const int wave = tid >> 6, lane = tid & 63;
    const int quad = lane >> 4, nl = lane & 15;
    const int nn = wave * 16 + nl;
    for (int i = tid; i < 1024; i += 256) pb_s[i] = pwb[i];
    const bf16* wb = wcp + (long)(mq * 128) * 512;
    const bf16* xb = dwout + ((long)b * 441 + nt * 63) * 512;
    int wm[4], wk[4];
    #pragma unroll
    for (int i = 0; i < 4; ++i) { int u = tid + 256 * i; wm[i] = u >> 3; wk[i] = (u & 7) * 8; }
    int xp[2], xk[2];
    #pragma unroll
    for (int i = 0; i < 2; ++i) { int u = tid + 256 * i; xp[i] = u >> 3; xk[i] = (u & 7) * 8; }
    #pragma unroll
    for (int i = 0; i < 4; ++i)
        *(uint4*)&W_s[0][wm[i] * 72 + wk[i]] = *(const uint4*)&wb[wm[i] * 512 + wk[i]];
    #pragma unroll
    for (int i = 0; i < 2; ++i) {
        uint4 v = {0, 0, 0, 0};
        if (xp[i] < 63) v = *(const uint4*)&xb[xp[i] * 512 + xk[i]];
        *(uint4*)&X_s[0][xp[i] * 72 + xk[i]] = v;
    }
    __syncthreads();
    f32x4 acc[8];
    #pragma unroll
    for (int f = 0; f < 8; ++f) acc[f] = (f32x4){0.f, 0.f, 0.f, 0.f};
    for (int cc = 0; cc < 8; ++cc) {
        const bool ld = (cc + 1 < 8);
        uint4 wr[4], xr[2];
        if (ld) {
            #pragma unroll
            for (int i = 0; i < 4; ++i)
                wr[i] = *(const uint4*)&wb[wm[i] * 512 + (cc + 1) * 64 + wk[i]];
            #pragma unroll
            for (int i = 0; i < 2; ++i) {
                uint4 v = {0, 0, 0, 0};
                if (xp[i] < 63) v = *(const uint4*)&xb[xp[i] * 512 + (cc + 1) * 64 + xk[i]];
                xr[i] = v;
            }
        }
        const short* Wc = W_s[cc & 1];
        const short* Xc = X_s[cc & 1];
        #pragma unroll
        for (int s = 0; s < 2; ++s) {
            const bf16x8 bv = *(const bf16x8*)&Xc[nn * 72 + s * 32 + quad * 8];
            #pragma unroll
            for (int f = 0; f < 8; ++f) {
                bf16x8 af = *(const bf16x8*)&Wc[(f * 16 + nl) * 72 + s * 32 + quad * 8];
                acc[f] = __builtin_amdgcn_mfma_f32_16x16x32_bf16(af, bv, acc[f], 0, 0, 0);
            }
        }
        if (ld) {
            short* Wn = W_s[(cc + 1) & 1];
            short* Xn = X_s[(cc + 1) & 1];
            #pragma unroll
            for (int i = 0; i < 4; ++i) *(uint4*)&Wn[wm[i] * 72 + wk[i]] = wr[i];
            #pragma unroll
            for (int i = 0; i < 2; ++i) *(uint4*)&Xn[xp[i] * 72 + xk[i]] = xr[i];
        }
        __syncthreads();
    }
    if (nn < 63) {
        const int p = nt * 63 + nn;
        #pragma unroll
        for (int f = 0; f < 8; ++f) {
            const int ch = mq * 32 + f * 4 + quad;
            float ig = sigf(acc[f][0] + b2f(pb_s[ch]));
            float fg = sigf(acc[f][1] + b2f(pb_s[256 + ch]));
            float og = sigf(acc[f][2] + b2f(pb_s[512 + ch]));
            float gg = tanhfast(acc[f][3] + b2f(pb_s[768 + ch]));
            const int ci2 = (b * 441 + p) * 256 + ch;
            float c2 = fg * c[ci2] + ig * gg;
            float h2 = og * tanhfast(c2);
            c[ci2] = c2; h[ci2] = h2;
            hst[(long)b * 112896 + p * 256 + ch] = f2b(h2);
        }
    }
}

// K6: dec1 MFMA, r13 NAIVE single-buffer (45 KB, 3 blocks/CU). grid (4,4,32).
__global__ __launch_bounds__(256) void k_dec1_mfma(
    const bf16* __restrict__ feats, const bf16* __restrict__ hs0,
    const bf16* __restrict__ wc1, const bf16* __restrict__ bias,
    bf16* __restrict__ d1c, int c0f)
{
    __shared__ __align__(16) short H_s[184 * 72];
    __shared__ __align__(16) short W_s[128 * 72];
    const int nt = blockIdx.x, par = blockIdx.y, z = blockIdx.z;
    const int py = par >> 1, px = par & 1;
    const int n = c0f + z, bb = n >> 4, tt = n & 15;
    const short* hsf = (const short*)((tt == 0) ? (hs0 + (long)bb * 112896)
                        : (feats + (long)((tt - 1) * 8 + bb) * 112896));
    const int tid = threadIdx.x;
    const int wave = tid >> 6, lane = tid & 63;
    const int quad = lane >> 4, nl = lane & 15;
    int maxs = 440 - nt * 126; if (maxs > 125) maxs = 125;
    int hb[2], pv[2]; bool val[2];
    #pragma unroll
    for (int pg = 0; pg < 2; ++pg) {
        int slot = (wave * 2 + pg) * 16 + nl;
        val[pg] = (slot <= maxs);
        int sl = val[pg] ? slot : maxs;
        int p = nt * 126 + sl;
        pv[pg] = p;
        int y = p / 21, x = p % 21;
        hb[pg] = (y - nt * 6 + py) * 23 + (x + px);
    }
    f32x4 acc[2][8];
    #pragma unroll
    for (int pg = 0; pg < 2; ++pg)
        #pragma unroll
        for (int f = 0; f < 8; ++f) acc[pg][f] = (f32x4){0.f, 0.f, 0.f, 0.f};
    for (int cc = 0; cc < 4; ++cc) {
        __syncthreads();
        for (int u = tid; u < 1472; u += 256) {
            int rc = u >> 3, c8 = (u & 7) * 8;
            int gy = nt * 6 - 1 + rc / 23, gx = (rc % 23) - 1;
            uint4 v = {0, 0, 0, 0};
            if (gy >= 0 && gy < 21 && gx >= 0 && gx < 21)
                v = *(const uint4*)&hsf[(gy * 21 + gx) * 256 + cc * 64 + c8];
            *(uint4*)&H_s[rc * 72 + c8] = v;
        }
        for (int tap = 0; tap < 4; ++tap) {
            __syncthreads();
            for (int u = tid; u < 1024; u += 256) {
                int m = u >> 3, k8 = (u & 7) * 8;
                *(uint4*)&W_s[m * 72 + k8] =
                    *(const uint4*)&wc1[((par * 128 + m) << 10) + tap * 256 + cc * 64 + k8];
            }
            __syncthreads();
            const int a = tap >> 1, b = tap & 1;
            #pragma unroll
            for (int s = 0; s < 2; ++s) {
                bf16x8 bv0 = *(const bf16x8*)&H_s[(hb[0] + a * 23 + b) * 72 + s * 32 + quad * 8];
                bf16x8 bv1 = *(const bf16x8*)&H_s[(hb[1] + a * 23 + b) * 72 + s * 32 + quad * 8];
                #pragma unroll
                for (int f = 0; f < 8; ++f) {
                    bf16x8 af = *(const bf16x8*)&W_s[(f * 16 + nl) * 72 + s * 32 + quad * 8];
                    acc[0][f] = __builtin_amdgcn_mfma_f32_16x16x32_bf16(af, bv0, acc[0][f], 0, 0, 0);
                    acc[1][f] = __builtin_amdgcn_mfma_f32_16x16x32_bf16(af, bv1, acc[1][f], 0, 0, 0);
                }
            }
        }
    }
    #pragma unroll
    for (int pg = 0; pg < 2; ++pg) {
        if (!val[pg]) continue;
        const int p = pv[pg];
        const int oy = 2 * (p / 21) + py, ox = 2 * (p % 21) + px;
        #pragma unroll
        for (int f = 0; f < 8; ++f) {
            ushort4 o;
            unsigned short* op = (unsigned short*)&o;
            #pragma unroll
            for (int reg = 0; reg < 4; ++reg) {
                const int oc = f * 16 + quad * 4 + reg;
                op[reg] = f2u(fmaxf(acc[pg][f][reg] + b2f(bias[oc]), 0.f));
            }
            *(ushort4*)&d1c[((long)z * 1764 + oy * 42 + ox) * 128 +
                            f * 16 + quad * 4] = o;
        }
    }
}

// K7: dec2 MFMA fused w3-reduce, W-pipelined (r14). grid (14,4,32).
__global__ __launch_bounds__(256) void k_dec2f_mfma(
    const bf16* __restrict__ d1c, const bf16* __restrict__ wc2,
    const bf16* __restrict__ bias, const bf16* __restrict__ w3,
    const bf16* __restrict__ b3, void* __restrict__ out, int c0f,
    const int* __restrict__ flag)
{
    __shared__ __align__(16) short H_s[220 * 72];
    __shared__ __align__(16) short W_s[2][64 * 72];
    const int nt = blockIdx.x, par = blockIdx.y, z = blockIdx.z;
    const int py = par >> 1, px = par & 1;
    const int tid = threadIdx.x;
    const int wave = tid >> 6, lane = tid & 63;
    const int quad = lane >> 4, nl = lane & 15;
    int hb[2], pv[2]; bool val[2];
    #pragma unroll
    for (int pg = 0; pg < 2; ++pg) {
        int slot = (wave * 2 + pg) * 16 + nl;
        val[pg] = (slot < 126);
        int sl = val[pg] ? slot : 125;
        int p = nt * 126 + sl;
        pv[pg] = p;
        int y = p / 42, x = p % 42;
        hb[pg] = (y - nt * 3 + py) * 44 + (x + px);
    }
    const bf16* wbase = wc2 + ((long)(par * 64) << 9);
    const int wm0 = tid >> 3, wk0 = (tid & 7) * 8;
    const int wm1 = (tid + 256) >> 3, wk1 = ((tid + 256) & 7) * 8;
    for (int u = tid; u < 1760; u += 256) {
        int rc = u >> 3, c8 = (u & 7) * 8;
        int gy = nt * 3 - 1 + rc / 44, gx = (rc % 44) - 1;
        uint4 v = {0, 0, 0, 0};
        if (gy >= 0 && gy < 42 && gx >= 0 && gx < 42)
            v = *(const uint4*)&d1c[((long)z * 1764 + gy * 42 + gx) * 128 + c8];
        *(uint4*)&H_s[rc * 72 + c8] = v;
    }
    *(uint4*)&W_s[0][wm0 * 72 + wk0] = *(const uint4*)&wbase[wm0 * 512 + wk0];
    *(uint4*)&W_s[0][wm1 * 72 + wk1] = *(const uint4*)&wbase[wm1 * 512 + wk1];
    __syncthreads();
    f32x4 acc[2][4];
    #pragma unroll
    for (int pg = 0; pg < 2; ++pg)
        #pragma unroll
        for (int f = 0; f < 4; ++f) acc[pg][f] = (f32x4){0.f, 0.f, 0.f, 0.f};
    for (int it = 0; it < 8; ++it) {
        const int cc = it >> 2, tap = it & 3;
        const bool ld = (it + 1 < 8);
        uint4 wr0, wr1;
        if (ld) {
            const int ncc = (it + 1) >> 2, ntap = (it + 1) & 3;
            const bf16* src = wbase + ntap * 128 + ncc * 64;
            wr0 = *(const uint4*)&src[wm0 * 512 + wk0];
            wr1 = *(const uint4*)&src[wm1 * 512 + wk1];
        }
        const int a = tap >> 1, b = tap & 1;
        const short* Wc = W_s[it & 1];
        #pragma unroll
        for (int s = 0; s < 2; ++s) {
            bf16x8 bv0 = *(const bf16x8*)&H_s[(hb[0] + a * 44 + b) * 72 + s * 32 + quad * 8];
            bf16x8 bv1 = *(const bf16x8*)&H_s[(hb[1] + a * 44 + b) * 72 + s * 32 + quad * 8];
            #pragma unroll
            for (int f = 0; f < 4; ++f) {
                bf16x8 af = *(const bf16x8*)&Wc[(f * 16 + nl) * 72 + s * 32 + quad * 8];
                acc[0][f] = __builtin_amdgcn_mfma_f32_16x16x32_bf16(af, bv0, acc[0][f], 0, 0, 0);
                acc[1][f] = __builtin_amdgcn_mfma_f32_16x16x32_bf16(af, bv1, acc[1][f], 0, 0, 0);
            }
        }
        if (ld) {
            short* Wn = W_s[(it + 1) & 1];
            *(uint4*)&Wn[wm0 * 72 + wk0] = wr0;
            *(uint4*)&Wn[wm1 * 72 + wk1] = wr1;
        }
        __syncthreads();
        if (tap == 3 && cc == 0) {
            for (int u = tid; u < 1760; u += 256) {
                int rc = u >> 3, c8 = (u & 7) * 8;
                int gy = nt * 3 - 1 + rc / 44, gx = (rc % 44) - 1;
                uint4 v = {0, 0, 0, 0};
                if (gy >= 0 && gy < 42 && gx >= 0 && gx < 42)
                    v = *(const uint4*)&d1c[((long)z * 1764 + gy * 42 + gx) * 128 + 64 + c8];
                *(uint4*)&H_s[rc * 72 + c8] = v;
            }
            __syncthreads();
        }
    }
    #pragma unroll
    for (int pg = 0; pg < 2; ++pg) {
        float part = 0.f;
        #pragma unroll
        for (int f = 0; f < 4; ++f)
            #pragma unroll
            for (int reg = 0; reg < 4; ++reg) {
                const int oc = f * 16 + quad * 4 + reg;
                part += b2f(w3[oc]) * fmaxf(acc[pg][f][reg] + b2f(bias[oc]), 0.f);
            }
        part += __shfl_xor(part, 16);
        part += __shfl_xor(part, 32);
        if (quad == 0 && val[pg]) {
            const int p = pv[pg];
            const int oy = 2 * (p / 42) + py, ox = 2 * (p % 42) + px;
            const float v = part + b2f(b3[0]);
            const long oi = (long)(c0f + z) * 7056 + oy * 84 + ox;
            if (*flag) ((float*)out)[oi] = v;
            else       ((bf16*)out)[oi]  = f2b(v);
        }
    }
}

// K9: flush final h,c (NHWC f32) -> d_out (NCHW)
__global__ __launch_bounds__(256) void k_out_hc(
    const float* __restrict__ h, const float* __restrict__ c,
    void* __restrict__ out, const int* __restrict__ flag)
{
    int idx = blockIdx.x * 256 + threadIdx.x;
    if (idx >= 903168) return;
    const int ch = idx & 255;
    const int r = idx >> 8;
    const int p = r % 441, b = r / 441;
    const long o = (long)(b * 256 + ch) * 441 + p;
    if (*flag) {
        ((float*)out)[903168 + o] = h[idx];
        ((float*)out)[1806336 + o] = c[idx];
    } else {
        ((bf16*)out)[903168 + o]  = f2b(h[idx]);
        ((bf16*)out)[1806336 + o] = f2b(c[idx]);
    }
}

extern "C" void kernel_launch(void* const* d_in, const int* in_sizes, int n_in,
                              void* d_out, int out_size, void* d_ws, size_t ws_size,
                              hipStream_t stream)
{
    char* wsb = (char*)d_ws;
    static const long woff[15] = {0, 3456, 3584, 151040, 151296, 741120, 741632,
                                  750848, 1799424, 1801472, 2391296, 2391552,
                                  2539008, 2539136, 2539264};
    const long FLAG_OFF = 2539280;
    const long WC1_OFF = 2539296;
    const long WC2_OFF = 3587872;
    const long WCP_OFF = 3850016;
    const long WC3_OFF = 4898592;
    const long WC2E_OFF = 5488416;
    const long WC1E_OFF = 5635872;
    const long DWT_OFF  = 5639968;
    const long CE = 5649184;
    int* flag = (int*)(wsb + FLAG_OFF);

    k_detect<<<1, 256, 0, stream>>>((const unsigned short*)d_in[0], 8192, flag);
    CanonSrc cs;
    for (int i = 0; i < 15; ++i) cs.s[i] = d_in[i + 1];
    k_canon_all<<<(1269633 + 255) / 256, 256, 0, stream>>>(cs, wsb, 1269633, flag);
    k_prep_all<<<6074, 256, 0, stream>>>(wsb);

    const void* x = d_in[0];
    bf16 *enc_b1 = (bf16*)(wsb + woff[1]),
         *enc_b2 = (bf16*)(wsb + woff[3]), *enc_b3 = (bf16*)(wsb + woff[5]),
         *pw_b   = (bf16*)(wsb + woff[8]),
         *dec_b1 = (bf16*)(wsb + woff[10]),
         *dec_b2 = (bf16*)(wsb + woff[12]), *dec_w3 = (bf16*)(wsb + woff[13]),
         *dec_b3 = (bf16*)(wsb + woff[14]);
    bf16* wc1  = (bf16*)(wsb + WC1_OFF);
    bf16* wc2  = (bf16*)(wsb + WC2_OFF);
    bf16* wcp  = (bf16*)(wsb + WCP_OFF);
    bf16* wc3  = (bf16*)(wsb + WC3_OFF);
    bf16* wc2e = (bf16*)(wsb + WC2E_OFF);
    bf16* wc1e = (bf16*)(wsb + WC1E_OFF);
    bf16* dwt  = (bf16*)(wsb + DWT_OFF);

    bf16*  feats = (bf16*)(wsb + CE);                  // 28,901,376 (t-major)
    bf16*  hs0   = (bf16*)(wsb + CE + 28901376);       //  1,806,336
    float* hbuf  = (float*)(wsb + CE + 30707712);      //  3,612,672
    float* cbuf  = (float*)(wsb + CE + 34320384);      //  3,612,672
    bf16*  d1c   = (bf16*)(wsb + CE + 37933056);       // 14,450,688 (decode)
    bf16*  p1c   = (bf16*)(wsb + CE + 37933056);       // 14,450,688 (encode, 64 fr)
    bf16*  p2c   = (bf16*)(wsb + CE + 28901376);       //  7,225,344 (encode alias)
    bf16*  dwout = (bf16*)(wsb + CE + 52383744);       //  3,612,672 (LSTM)

    for (int f0 = 0; f0 < 128; f0 += 64) {
        k_conv1_mfma<<<dim3(28, 1, 64), 256, 0, stream>>>(x, wc1e, enc_b1, p1c, f0, flag);
        k_conv2_mfma<<<dim3(7, 1, 64), 256, 0, stream>>>(p1c, wc2e, enc_b2, p2c);
        k_conv3_mfma<<<dim3(7, 2, 64), 256, 0, stream>>>(p2c, wc3, enc_b3, feats, f0);
    }
    hipMemsetAsync(hbuf, 0, 2 * 3612672, stream);
    for (int t = 0; t < 16; ++t) {
        bf16* hst = (t == 0) ? hs0 : (feats + (long)(t - 1) * 8 * 112896);
        k_dw_vec<<<882, 256, 0, stream>>>(feats, hbuf, dwt, dwout, t);
        k_pw_mfma<<<dim3(7, 8, 8), 256, 0, stream>>>(dwout, wcp, pw_b, hbuf, cbuf, hst);
    }
    k_out_hc<<<3528, 256, 0, stream>>>(hbuf, cbuf, d_out, flag);
    for (int c0f = 0; c0f < 128; c0f += 32) {
        k_dec1_mfma<<<dim3(4, 4, 32), 256, 0, stream>>>(feats, hs0, wc1, dec_b1, d1c, c0f);
        k_dec2f_mfma<<<dim3(14, 4, 32), 256, 0, stream>>>(d1c, wc2, dec_b2, dec_w3,
                                                          dec_b3, d_out, c0f, flag);
    }
}

// Round 20
// 1159.847 us; speedup vs baseline: 1.0132x; 1.0132x over previous
//
#include <hip/hip_runtime.h>
#include <hip/hip_bf16.h>

typedef __hip_bfloat16 bf16;
typedef __attribute__((ext_vector_type(8))) short bf16x8;   // 8 bf16 (4 VGPRs)
typedef __attribute__((ext_vector_type(4))) float f32x4;    // 4 fp32 acc
#define DEV static __device__ __forceinline__

DEV float b2f(bf16 v) { return __bfloat162float(v); }
DEV bf16  f2b(float v) { return __float2bfloat16(v); }
DEV unsigned short f2u(float v) { bf16 t = f2b(v); return *(unsigned short*)&t; }
DEV float u2f(unsigned short u) { bf16 t = *(bf16*)&u; return __bfloat162float(t); }
DEV float sigf(float x) { return 1.0f / (1.0f + __expf(-x)); }
DEV float tanhfast(float x) { return 2.0f / (1.0f + __expf(-2.0f * x)) - 1.0f; }

// ---------------------------------------------------------------------------
// fp32 I/O (proved r4). Round-20: base = round 17/19 (1175 us, verified).
// Single safe delta: k_out_hc fused into the t=15 k_pw_mfma (its grid covers
// exactly all (b,ch,p) of h/c; epilogue already holds h2/c2 in registers) —
// one fewer launch + 10.8 MB less traffic. All other kernels byte-identical.
// ws layout unchanged (end 61.6 MB <= 63.95 MB confirmed).
// ---------------------------------------------------------------------------

__global__ void k_detect(const unsigned short* __restrict__ xb, int nscan, int* flag)
{
    __shared__ int cnt_s[256];
    int tid = threadIdx.x;
    int c = 0;
    for (int i = tid; i < nscan; i += 256) {
        unsigned int e = (xb[i] >> 7) & 0xFF;
        c += (e >= 0xC0);
    }
    cnt_s[tid] = c;
    __syncthreads();
    for (int off = 128; off > 0; off >>= 1) {
        if (tid < off) cnt_s[tid] += cnt_s[tid + off];
        __syncthreads();
    }
    if (tid == 0) *flag = (cnt_s[0] > 256) ? 1 : 0;
}

struct CanonSrc { const void* s[15]; };

__global__ __launch_bounds__(256) void k_canon_all(
    CanonSrc cs, char* __restrict__ wsb, int total, const int* __restrict__ flag)
{
    static const __device__ int off_d[16] = {0, 1728, 1792, 75520, 75648, 370560,
        370816, 375424, 899712, 900736, 1195648, 1195776, 1269504, 1269568,
        1269632, 1269633};
    static const __device__ long woff_d[15] = {0, 3456, 3584, 151040, 151296,
        741120, 741632, 750848, 1799424, 1801472, 2391296, 2391552, 2539008,
        2539136, 2539264};
    int i = blockIdx.x * 256 + threadIdx.x;
    if (i >= total) return;
    int t = 0;
    while (t < 14 && i >= off_d[t + 1]) ++t;
    int j = i - off_d[t];
    bf16* dst = (bf16*)(wsb + woff_d[t]);
    if (*flag) dst[j] = f2b(((const float*)cs.s[t])[j]);
    else       dst[j] = ((const bf16*)cs.s[t])[j];
}

__global__ __launch_bounds__(256) void k_prep_all(char* __restrict__ wsb)
{
    long gid = (long)blockIdx.x * 256 + threadIdx.x;
    if (gid < 524288) {
        int idx = (int)gid;
        const bf16* w = (const bf16*)(wsb + 1801472);
        bf16* wc1 = (bf16*)(wsb + 2539296);
        int ci = idx & 255, tap = (idx >> 8) & 3;
        int oc = (idx >> 10) & 127, par = idx >> 17;
        int a = tap >> 1, b = tap & 1;
        int py = par >> 1, px = par & 1;
        const bf16* wb = w + (oc * 256 + ci) * 9;
        float v = 0.f;
        #pragma unroll
        for (int ky = 0; ky < 3; ++ky) {
            bool rok = (py == 0) ? (a == 0 ? (ky == 0) : (ky >= 1))
                                 : (a == 0 ? (ky <= 1) : (ky == 2));
            if (!rok) continue;
            #pragma unroll
            for (int kx = 0; kx < 3; ++kx) {
                bool cok = (px == 0) ? (b == 0 ? (kx == 0) : (kx >= 1))
                                     : (b == 0 ? (kx <= 1) : (kx == 2));
                if (cok) v += b2f(wb[ky * 3 + kx]);
            }
        }
        wc1[idx] = f2b(v);
    } else if (gid < 655360) {
        int idx = (int)(gid - 524288);
        const bf16* w = (const bf16*)(wsb + 2391552);
        bf16* wc2 = (bf16*)(wsb + 3587872);
        int ci = idx & 127, tap = (idx >> 7) & 3;
        int oc = (idx >> 9) & 63, par = idx >> 15;
        int a = tap >> 1, b = tap & 1;
        int py = par >> 1, px = par & 1;
        const bf16* wb = w + (oc * 128 + ci) * 9;
        float v = 0.f;
        #pragma unroll
        for (int ky = 0; ky < 3; ++ky) {
            bool rok = (py == 0) ? (a == 0 ? (ky == 0) : (ky >= 1))
                                 : (a == 0 ? (ky <= 1) : (ky == 2));
            if (!rok) continue;
            #pragma unroll
            for (int kx = 0; kx < 3; ++kx) {
                bool cok = (px == 0) ? (b == 0 ? (kx == 0) : (kx >= 1))
                                     : (b == 0 ? (kx <= 1) : (kx == 2));
                if (cok) v += b2f(wb[ky * 3 + kx]);
            }
        }
        wc2[idx] = f2b(v);
    } else if (gid < 1179648) {
        int idx = (int)(gid - 655360);
        const bf16* pww = (const bf16*)(wsb + 750848);
        bf16* wcp = (bf16*)(wsb + 3850016);
        int k = idx & 511, m = idx >> 9;
        int ch = m >> 2, gate = m & 3;
        wcp[idx] = pww[(gate * 256 + ch) * 512 + k];
    } else if (gid < 1474560) {
        int idx = (int)(gid - 1179648);
        const bf16* w = (const bf16*)(wsb + 151296);
        bf16* wc3 = (bf16*)(wsb + 4898592);
        int oc = idx / 1152, rem = idx % 1152;
        int tap = rem >> 7, ci = rem & 127;
        wc3[idx] = w[(oc * 128 + ci) * 9 + tap];
    } else if (gid < 1548288) {
        int idx = (int)(gid - 1474560);
        const bf16* w = (const bf16*)(wsb + 3584);
        bf16* wc2e = (bf16*)(wsb + 5488416);
        int oc = idx / 576, rem = idx % 576;
        int tap = rem >> 6, ci = rem & 63;
        wc2e[idx] = w[(oc * 64 + ci) * 9 + tap];
    } else if (gid < 1550336) {
        int idx = (int)(gid - 1548288);
        const bf16* w = (const bf16*)(wsb + 0);
        bf16* wc1e = (bf16*)(wsb + 5635872);
        int oc = idx >> 5, k = idx & 31;
        bf16 v = f2b(0.f);
        if (k < 27) v = w[oc * 27 + k];
        wc1e[idx] = v;
    } else if (gid < 1554944) {
        int idx = (int)(gid - 1550336);
        const bf16* w = (const bf16*)(wsb + 741632);
        bf16* dwt = (bf16*)(wsb + 5639968);
        int tap = idx >> 9, ch = idx & 511;
        dwt[idx] = w[ch * 9 + tap];
    }
}

// K1: conv 3->64 + relu + pool via MFMA, parity-fused.
__global__ __launch_bounds__(256) void k_conv1_mfma(
    const void* __restrict__ xv, const bf16* __restrict__ wc1e,
    const bf16* __restrict__ bias, bf16* __restrict__ p1c, int fbase,
    const int* __restrict__ flag)
{
    __shared__ __align__(16) short W_s[64 * 40];
    __shared__ __align__(16) short H_s[3 * 6 * 88];
    const int nt = blockIdx.x, z = blockIdx.z;
    const int n = fbase + z;
    const int tid = threadIdx.x;
    const int wave = tid >> 6, lane = tid & 63;
    const int quad = lane >> 4, nl = lane & 15;
    const int nn = wave * 16 + nl;
    const int p0 = nt * 63, y0 = p0 / 42;
    const int np = p0 + ((nn < 63) ? nn : 62);
    const int y = np / 42, xq = np % 42;
    const int isf32 = *flag;
    for (int u = tid; u < 256; u += 256) {
        int m = u >> 2, k8 = (u & 3) * 8;
        *(uint4*)&W_s[m * 40 + k8] = *(const uint4*)&wc1e[m * 32 + k8];
    }
    for (int i = tid; i < 1548; i += 256) {
        int ci = i / 516, rem = i % 516, r = rem / 86, col = rem % 86;
        int gy = 2 * y0 - 1 + r, gx = col - 1;
        float v = 0.f;
        if (gy >= 0 && gy < 84 && gx >= 0 && gx < 84) {
            int idx = (n * 3 + ci) * 7056 + gy * 84 + gx;
            v = isf32 ? ((const float*)xv)[idx] : b2f(((const bf16*)xv)[idx]);
        }
        H_s[(ci * 6 + r) * 88 + col] = f2u(v);
    }
    __syncthreads();
    bf16x8 af[4];
    #pragma unroll
    for (int f = 0; f < 4; ++f)
        af[f] = *(const bf16x8*)&W_s[(f * 16 + nl) * 40 + quad * 8];
    f32x4 acc[4][4];
    #pragma unroll
    for (int p = 0; p < 4; ++p)
        #pragma unroll
        for (int f = 0; f < 4; ++f) acc[p][f] = (f32x4){0.f, 0.f, 0.f, 0.f};
    const int yl = y - y0;
    #pragma unroll
    for (int par = 0; par < 4; ++par) {
        const int pa = par >> 1, pb = par & 1;
        bf16x8 bv;
        #pragma unroll
        for (int j = 0; j < 8; ++j) {
            int k = quad * 8 + j;
            short v = 0;
            if (k < 27) {
                int ci = k / 9, tap = k % 9;
                int dy = tap / 3, dx = tap % 3;
                v = H_s[(ci * 6 + 2 * yl + pa + dy) * 88 + 2 * xq + pb + dx];
            }
            bv[j] = v;
        }
        #pragma unroll
        for (int f = 0; f < 4; ++f)
            acc[par][f] = __builtin_amdgcn_mfma_f32_16x16x32_bf16(
                af[f], bv, acc[par][f], 0, 0, 0);
    }
    if (nn < 63) {
        #pragma unroll
        for (int f = 0; f < 4; ++f) {
            ushort4 o;
            unsigned short* op = (unsigned short*)&o;
            #pragma unroll
            for (int reg = 0; reg < 4; ++reg) {
                const int oc = f * 16 + quad * 4 + reg;
                float m = fmaxf(fmaxf(acc[0][f][reg], acc[1][f][reg]),
                                fmaxf(acc[2][f][reg], acc[3][f][reg]));
                op[reg] = f2u(fmaxf(m + b2f(bias[oc]), 0.f));
            }
            *(ushort4*)&p1c[((long)z * 1764 + np) * 64 + f * 16 + quad * 4] = o;
        }
    }
}

// K2: conv 64->128 + relu + maxpool via MFMA, parity-fused, W-pipelined (r14).
__global__ __launch_bounds__(256) void k_conv2_mfma(
    const bf16* __restrict__ p1c, const bf16* __restrict__ wc2e,
    const bf16* __restrict__ bias, bf16* __restrict__ p2c)
{
    __shared__ __align__(16) short H_s[352 * 72];
    __shared__ __align__(16) short W_s[2][128 * 40];
    const int nt = blockIdx.x, z = blockIdx.z;
    const int tid = threadIdx.x;
    const int wave = tid >> 6, lane = tid & 63;
    const int quad = lane >> 4, nl = lane & 15;
    const int nn = wave * 16 + nl;
    const int np = (nn < 63) ? nn : 62;
    const int iyl = np / 21, ix = np % 21;
    const int r0 = nt * 3;
    for (int u = tid; u < 2816; u += 256) {
        int rc = u >> 3, c8 = u & 7;
        int gy = 2 * r0 - 1 + rc / 44, gx = (rc % 44) - 1;
        uint4 v = {0, 0, 0, 0};
        if (gy >= 0 && gy < 42 && gx >= 0 && gx < 42)
            v = *(const uint4*)&p1c[((long)z * 1764 + gy * 42 + gx) * 64 + c8 * 8];
        *(uint4*)&H_s[rc * 72 + c8 * 8] = v;
    }
    const int m0 = tid >> 2, k80 = (tid & 3) * 8;
    const int m1 = (tid + 256) >> 2, k81 = ((tid + 256) & 3) * 8;
    *(uint4*)&W_s[0][m0 * 40 + k80] = *(const uint4*)&wc2e[m0 * 576 + k80];
    *(uint4*)&W_s[0][m1 * 40 + k81] = *(const uint4*)&wc2e[m1 * 576 + k81];
    __syncthreads();
    f32x4 acc[4][8];
    #pragma unroll
    for (int p = 0; p < 4; ++p)
        #pragma unroll
        for (int f = 0; f < 8; ++f) acc[p][f] = (f32x4){0.f, 0.f, 0.f, 0.f};
    for (int it = 0; it < 18; ++it) {
        const int tap = it >> 1, cc = it & 1;
        const bool ld = (it + 1 < 18);
        uint4 wr0, wr1;
        if (ld) {
            const int ntap = (it + 1) >> 1, ncc = (it + 1) & 1;
            const bf16* src = wc2e + ntap * 64 + ncc * 32;
            wr0 = *(const uint4*)&src[m0 * 576 + k80];
            wr1 = *(const uint4*)&src[m1 * 576 + k81];
        }
        const int dy = tap / 3, dx = tap % 3;
        const short* Wc = W_s[it & 1];
        bf16x8 af[8];
        #pragma unroll
        for (int f = 0; f < 8; ++f)
            af[f] = *(const bf16x8*)&Wc[(f * 16 + nl) * 40 + quad * 8];
        #pragma unroll
        for (int par = 0; par < 4; ++par) {
            const int pa = par >> 1, pb = par & 1;
            const int hy = 2 * iyl + pa + dy;
            const int hx = 2 * ix + pb + dx;
            const bf16x8 bv =
                *(const bf16x8*)&H_s[(hy * 44 + hx) * 72 + cc * 32 + quad * 8];
            #pragma unroll
            for (int f = 0; f < 8; ++f)
                acc[par][f] = __builtin_amdgcn_mfma_f32_16x16x32_bf16(
                    af[f], bv, acc[par][f], 0, 0, 0);
        }
        if (ld) {
            short* Wn = W_s[(it + 1) & 1];
            *(uint4*)&Wn[m0 * 40 + k80] = wr0;
            *(uint4*)&Wn[m1 * 40 + k81] = wr1;
        }
        __syncthreads();
    }
    if (nn < 63) {
        #pragma unroll
        for (int f = 0; f < 8; ++f) {
            ushort4 o;
            unsigned short* op = (unsigned short*)&o;
            #pragma unroll
            for (int reg = 0; reg < 4; ++reg) {
                const int oc = f * 16 + quad * 4 + reg;
                float m = fmaxf(fmaxf(acc[0][f][reg], acc[1][f][reg]),
                                fmaxf(acc[2][f][reg], acc[3][f][reg]));
                op[reg] = f2u(fmaxf(m + b2f(bias[oc]), 0.f));
            }
            *(ushort4*)&p2c[((long)z * 441 + (r0 + iyl) * 21 + ix) * 128 +
                            f * 16 + quad * 4] = o;
        }
    }
}

// K3: conv 128->256 + relu via MFMA, W-pipelined (r14). grid (7,2,64).
__global__ __launch_bounds__(256) void k_conv3_mfma(
    const bf16* __restrict__ p2c, const bf16* __restrict__ wc3,
    const bf16* __restrict__ bias, bf16* __restrict__ feats, int fbase)
{
    __shared__ __align__(16) short H_s[115 * 136];
    __shared__ __align__(16) short W_s[2][128 * 40];
    const int nt = blockIdx.x, oq = blockIdx.y, z = blockIdx.z;
    const int n = fbase + z;
    const int slot = (n & 15) * 8 + (n >> 4);
    const int tid = threadIdx.x;
    const int wave = tid >> 6, lane = tid & 63;
    const int quad = lane >> 4, nl = lane & 15;
    const int nn = wave * 16 + nl;
    const int np = (nn < 63) ? nn : 62;
    const int iyl = np / 21, ox = np % 21;
    const int r0 = nt * 3;
    for (int u = tid; u < 1840; u += 256) {
        int rc = u >> 4, c8 = u & 15;
        int gy = r0 + rc / 23 - 1, gx = (rc % 23) - 1;
        uint4 v = {0, 0, 0, 0};
        if (gy >= 0 && gy < 21 && gx >= 0 && gx < 21)
            v = *(const uint4*)&p2c[((long)z * 441 + gy * 21 + gx) * 128 + c8 * 8];
        *(uint4*)&H_s[rc * 136 + c8 * 8] = v;
    }
    const bf16* wbase = wc3 + (long)(oq * 128) * 1152;
    const int m0 = tid >> 2, k80 = (tid & 3) * 8;
    const int m1 = (tid + 256) >> 2, k81 = ((tid + 256) & 3) * 8;
    *(uint4*)&W_s[0][m0 * 40 + k80] = *(const uint4*)&wbase[m0 * 1152 + k80];
    *(uint4*)&W_s[0][m1 * 40 + k81] = *(const uint4*)&wbase[m1 * 1152 + k81];
    __syncthreads();
    f32x4 acc[8];
    #pragma unroll
    for (int f = 0; f < 8; ++f) acc[f] = (f32x4){0.f, 0.f, 0.f, 0.f};
    const int hb = iyl * 23 + ox;
    for (int it = 0; it < 36; ++it) {
        const int tap = it >> 2, cc = it & 3;
        const bool ld = (it + 1 < 36);
        uint4 wr0, wr1;
        if (ld) {
            const int ntap = (it + 1) >> 2, ncc = (it + 1) & 3;
            const bf16* src = wbase + ntap * 128 + ncc * 32;
            wr0 = *(const uint4*)&src[m0 * 1152 + k80];
            wr1 = *(const uint4*)&src[m1 * 1152 + k81];
        }
        const int dy = tap / 3, dx = tap % 3;
        const int hofs = (hb + dy * 23 + dx) * 136;
        const bf16x8 bv = *(const bf16x8*)&H_s[hofs + cc * 32 + quad * 8];
        const short* Wc = W_s[it & 1];
        #pragma unroll
        for (int f = 0; f < 8; ++f) {
            bf16x8 af = *(const bf16x8*)&Wc[(f * 16 + nl) * 40 + quad * 8];
            acc[f] = __builtin_amdgcn_mfma_f32_16x16x32_bf16(af, bv, acc[f], 0, 0, 0);
        }
        if (ld) {
            short* Wn = W_s[(it + 1) & 1];
            *(uint4*)&Wn[m0 * 40 + k80] = wr0;
            *(uint4*)&Wn[m1 * 40 + k81] = wr1;
        }
        __syncthreads();
    }
    if (nn < 63) {
        const int oy = r0 + iyl;
        #pragma unroll
        for (int f = 0; f < 8; ++f) {
            ushort4 o;
            unsigned short* op = (unsigned short*)&o;
            #pragma unroll
            for (int reg = 0; reg < 4; ++reg) {
                const int oc = oq * 128 + f * 16 + quad * 4 + reg;
                op[reg] = f2u(fmaxf(acc[f][reg] + b2f(bias[oc]), 0.f));
            }
            *(ushort4*)&feats[((long)slot * 441 + oy * 21 + ox) * 256 +
                              oq * 128 + f * 16 + quad * 4] = o;
        }
    }
}

// K4: depthwise 3x3, vectorized 8ch/thread -> dwout[b][441][512] bf16.
__global__ __launch_bounds__(256) void k_dw_vec(
    const bf16* __restrict__ feats, const float* __restrict__ h,
    const bf16* __restrict__ dwt, bf16* __restrict__ dwout, int t)
{
    int idx = blockIdx.x * 256 + threadIdx.x;
    if (idx >= 8 * 441 * 64) return;
    const int cg = idx & 63;
    const int p = (idx >> 6) % 441;
    const int b = idx / (441 * 64);
    const int ch = cg * 8;
    const int y = p / 21, x = p % 21;
    const bf16* fslot = feats + (long)(t * 8 + b) * 112896;
    const float* hb_ = h + (long)b * 112896;
    float a8[8];
    #pragma unroll
    for (int j = 0; j < 8; ++j) a8[j] = 0.f;
    #pragma unroll
    for (int ky = 0; ky < 3; ++ky) {
        int ny = y + ky - 1;
        if (ny < 0 || ny >= 21) continue;
        #pragma unroll
        for (int kx = 0; kx < 3; ++kx) {
            int nx = x + kx - 1;
            if (nx < 0 || nx >= 21) continue;
            const int tap = ky * 3 + kx;
            const bf16x8 wv = *(const bf16x8*)&dwt[tap * 512 + ch];
            if (ch < 256) {
                const bf16x8 xv = *(const bf16x8*)&fslot[(ny * 21 + nx) * 256 + ch];
                #pragma unroll
                for (int j = 0; j < 8; ++j)
                    a8[j] += u2f(((unsigned short*)&wv)[j]) *
                             u2f(((unsigned short*)&xv)[j]);
            } else {
                const float4 x0 = *(const float4*)&hb_[(ny * 21 + nx) * 256 + ch - 256];
                const float4 x1 = *(const float4*)&hb_[(ny * 21 + nx) * 256 + ch - 252];
                const float xf[8] = {x0.x, x0.y, x0.z, x0.w, x1.x, x1.y, x1.z, x1.w};
                #pragma unroll
                for (int j = 0; j < 8; ++j)
                    a8[j] += u2f(((unsigned short*)&wv)[j]) * xf[j];
            }
        }
    }
    ushort4 o0, o1;
    #pragma unroll
    for (int j = 0; j < 4; ++j) {
        ((unsigned short*)&o0)[j] = f2u(a8[j]);
        ((unsigned short*)&o1)[j] = f2u(a8[4 + j]);
    }
    *(ushort4*)&dwout[((long)b * 441 + p) * 512 + ch] = o0;
    *(ushort4*)&dwout[((long)b * 441 + p) * 512 + ch + 4] = o1;
}

// K5: pointwise + gates via MFMA, W/X LDS double-buffer 1-barrier (r14);
// when last==1 also writes final h,c to d_out (NCHW, dual-dtype) — fuses
// the old k_out_hc.
__global__ __launch_bounds__(256) void k_pw_mfma(
    const bf16* __restrict__ dwout, const bf16* __restrict__ wcp,
    const bf16* __restrict__ pwb, float* __restrict__ h, float* __restrict__ c,
    bf16* __restrict__ hst, void* __restrict__ out,
    const int* __restrict__ flag, int last)
{
    __shared__ __align__(16) short W_s[2][128 * 72];
    __shared__ __align__(16) short X_s[2][64 * 72];
    __shared__ bf16 pb_s[1024];
    const int nt = blockIdx.x, mq = blockIdx.y, b = blockIdx.z;
    const int tid = threadIdx.x;
    const int wave = tid >> 6, lane = tid & 63;
    const int quad = lane >> 4, nl = lane & 15;
    const int nn = wave * 16 + nl;
    for (int i = tid; i < 1024; i += 256) pb_s[i] = pwb[i];
    const bf16* wb = wcp + (long)(mq * 128) * 512;
    const bf16* xb = dwout + ((long)b * 441 + nt * 63) * 512;
    int wm[4], wk[4];
    #pragma unroll
    for (int i = 0; i < 4; ++i) { int u = tid + 256 * i; wm[i] = u >> 3; wk[i] = (u & 7) * 8; }
    int xp[2], xk[2];
    #pragma unroll
    for (int i = 0; i < 2; ++i) { int u = tid + 256 * i; xp[i] = u >> 3; xk[i] = (u & 7) * 8; }
    #pragma unroll
    for (int i = 0; i < 4; ++i)
        *(uint4*)&W_s[0][wm[i] * 72 + wk[i]] = *(const uint4*)&wb[wm[i] * 512 + wk[i]];
    #pragma unroll
    for (int i = 0; i < 2; ++i) {
        uint4 v = {0, 0, 0, 0};
        if (xp[i] < 63) v = *(const uint4*)&xb[xp[i] * 512 + xk[i]];
        *(uint4*)&X_s[0][xp[i] * 72 + xk[i]] = v;
    }
    __syncthreads();
    f32x4 acc[8];
    #pragma unroll
    for (int f = 0; f < 8; ++f) acc[f] = (f32x4){0.f, 0.f, 0.f, 0.f};
    for (int cc = 0; cc < 8; ++cc) {
        const bool ld = (cc + 1 < 8);
        uint4 wr[4], xr[2];
        if (ld) {
            #pragma unroll
            for (int i = 0; i < 4; ++i)
                wr[i] = *(const uint4*)&wb[wm[i] * 512 + (cc + 1) * 64 + wk[i]];
            #pragma unroll
            for (int i = 0; i < 2; ++i) {
                uint4 v = {0, 0, 0, 0};
                if (xp[i] < 63) v = *(const uint4*)&xb[xp[i] * 512 + (cc + 1) * 64 + xk[i]];
                xr[i] = v;
            }
        }
        const short* Wc = W_s[cc & 1];
        const short* Xc = X_s[cc & 1];
        #pragma unroll
        for (int s = 0; s < 2; ++s) {
            const bf16x8 bv = *(const bf16x8*)&Xc[nn * 72 + s * 32 + quad * 8];
            #pragma unroll
            for (int f = 0; f < 8; ++f) {
                bf16x8 af = *(const bf16x8*)&Wc[(f * 16 + nl) * 72 + s * 32 + quad * 8];
                acc[f] = __builtin_amdgcn_mfma_f32_16x16x32_bf16(af, bv, acc[f], 0, 0, 0);
            }
        }
        if (ld) {
            short* Wn = W_s[(cc + 1) & 1];
            short* Xn = X_s[(cc + 1) & 1];
            #pragma unroll
            for (int i = 0; i < 4; ++i) *(uint4*)&Wn[wm[i] * 72 + wk[i]] = wr[i];
            #pragma unroll
            for (int i = 0; i < 2; ++i) *(uint4*)&Xn[xp[i] * 72 + xk[i]] = xr[i];
        }
        __syncthreads();
    }
    if (nn < 63) {
        const int p = nt * 63 + nn;
        const int isf32 = last ? *flag : 0;
        #pragma unroll
        for (int f = 0; f < 8; ++f) {
            const int ch = mq * 32 + f * 4 + quad;
            float ig = sigf(acc[f][0] + b2f(pb_s[ch]));
            float fg = sigf(acc[f][1] + b2f(pb_s[256 + ch]));
            float og = sigf(acc[f][2] + b2f(pb_s[512 + ch]));
            float gg = tanhfast(acc[f][3] + b2f(pb_s[768 + ch]));
            const int ci2 = (b * 441 + p) * 256 + ch;
            float c2 = fg * c[ci2] + ig * gg;
            float h2 = og * tanhfast(c2);
            c[ci2] = c2; h[ci2] = h2;
            hst[(long)b * 112896 + p * 256 + ch] = f2b(h2);
            if (last) {
                const long o = (long)(b * 256 + ch) * 441 + p;
                if (isf32) {
                    ((float*)out)[903168 + o]  = h2;
                    ((float*)out)[1806336 + o] = c2;
                } else {
                    ((bf16*)out)[903168 + o]  = f2b(h2);
                    ((bf16*)out)[1806336 + o] = f2b(c2);
                }
            }
        }
    }
}

// K6: dec1 MFMA, r13 NAIVE single-buffer (45 KB, 3 blocks/CU). grid (4,4,32).
__global__ __launch_bounds__(256) void k_dec1_mfma(
    const bf16* __restrict__ feats, const bf16* __restrict__ hs0,
    const bf16* __restrict__ wc1, const bf16* __restrict__ bias,
    bf16* __restrict__ d1c, int c0f)
{
    __shared__ __align__(16) short H_s[184 * 72];
    __shared__ __align__(16) short W_s[128 * 72];
    const int nt = blockIdx.x, par = blockIdx.y, z = blockIdx.z;
    const int py = par >> 1, px = par & 1;
    const int n = c0f + z, bb = n >> 4, tt = n & 15;
    const short* hsf = (const short*)((tt == 0) ? (hs0 + (long)bb * 112896)
                        : (feats + (long)((tt - 1) * 8 + bb) * 112896));
    const int tid = threadIdx.x;
    const int wave = tid >> 6, lane = tid & 63;
    const int quad = lane >> 4, nl = lane & 15;
    int maxs = 440 - nt * 126; if (maxs > 125) maxs = 125;
    int hb[2], pv[2]; bool val[2];
    #pragma unroll
    for (int pg = 0; pg < 2; ++pg) {
        int slot = (wave * 2 + pg) * 16 + nl;
        val[pg] = (slot <= maxs);
        int sl = val[pg] ? slot : maxs;
        int p = nt * 126 + sl;
        pv[pg] = p;
        int y = p / 21, x = p % 21;
        hb[pg] = (y - nt * 6 + py) * 23 + (x + px);
    }
    f32x4 acc[2][8];
    #pragma unroll
    for (int pg = 0; pg < 2; ++pg)
        #pragma unroll
        for (int f = 0; f < 8; ++f) acc[pg][f] = (f32x4){0.f, 0.f, 0.f, 0.f};
    for (int cc = 0; cc < 4; ++cc) {
        __syncthreads();
        for (int u = tid; u < 1472; u += 256) {
            int rc = u >> 3, c8 = (u & 7) * 8;
            int gy = nt * 6 - 1 + rc / 23, gx = (rc % 23) - 1;
            uint4 v = {0, 0, 0, 0};
            if (gy >= 0 && gy < 21 && gx >= 0 && gx < 21)
                v = *(const uint4*)&hsf[(gy * 21 + gx) * 256 + cc * 64 + c8];
            *(uint4*)&H_s[rc * 72 + c8] = v;
        }
        for (int tap = 0; tap < 4; ++tap) {
            __syncthreads();
            for (int u = tid; u < 1024; u += 256) {
                int m = u >> 3, k8 = (u & 7) * 8;
                *(uint4*)&W_s[m * 72 + k8] =
                    *(const uint4*)&wc1[((par * 128 + m) << 10) + tap * 256 + cc * 64 + k8];
            }
            __syncthreads();
            const int a = tap >> 1, b = tap & 1;
            #pragma unroll
            for (int s = 0; s < 2; ++s) {
                bf16x8 bv0 = *(const bf16x8*)&H_s[(hb[0] + a * 23 + b) * 72 + s * 32 + quad * 8];
                bf16x8 bv1 = *(const bf16x8*)&H_s[(hb[1] + a * 23 + b) * 72 + s * 32 + quad * 8];
                #pragma unroll
                for (int f = 0; f < 8; ++f) {
                    bf16x8 af = *(const bf16x8*)&W_s[(f * 16 + nl) * 72 + s * 32 + quad * 8];
                    acc[0][f] = __builtin_amdgcn_mfma_f32_16x16x32_bf16(af, bv0, acc[0][f], 0, 0, 0);
                    acc[1][f] = __builtin_amdgcn_mfma_f32_16x16x32_bf16(af, bv1, acc[1][f], 0, 0, 0);
                }
            }
        }
    }
    #pragma unroll
    for (int pg = 0; pg < 2; ++pg) {
        if (!val[pg]) continue;
        const int p = pv[pg];
        const int oy = 2 * (p / 21) + py, ox = 2 * (p % 21) + px;
        #pragma unroll
        for (int f = 0; f < 8; ++f) {
            ushort4 o;
            unsigned short* op = (unsigned short*)&o;
            #pragma unroll
            for (int reg = 0; reg < 4; ++reg) {
                const int oc = f * 16 + quad * 4 + reg;
                op[reg] = f2u(fmaxf(acc[pg][f][reg] + b2f(bias[oc]), 0.f));
            }
            *(ushort4*)&d1c[((long)z * 1764 + oy * 42 + ox) * 128 +
                            f * 16 + quad * 4] = o;
        }
    }
}

// K7: dec2 MFMA fused w3-reduce, W-pipelined (r14). grid (14,4,32).
__global__ __launch_bounds__(256) void k_dec2f_mfma(
    const bf16* __restrict__ d1c, const bf16* __restrict__ wc2,
    const bf16* __restrict__ bias, const bf16* __restrict__ w3,
    const bf16* __restrict__ b3, void* __restrict__ out, int c0f,
    const int* __restrict__ flag)
{
    __shared__ __align__(16) short H_s[220 * 72];
    __shared__ __align__(16) short W_s[2][64 * 72];
    const int nt = blockIdx.x, par = blockIdx.y, z = blockIdx.z;
    const int py = par >> 1, px = par & 1;
    const int tid = threadIdx.x;
    const int wave = tid >> 6, lane = tid & 63;
    const int quad = lane >> 4, nl = lane & 15;
    int hb[2], pv[2]; bool val[2];
    #pragma unroll
    for (int pg = 0; pg < 2; ++pg) {
        int slot = (wave * 2 + pg) * 16 + nl;
        val[pg] = (slot < 126);
        int sl = val[pg] ? slot : 125;
        int p = nt * 126 + sl;
        pv[pg] = p;
        int y = p / 42, x = p % 42;
        hb[pg] = (y - nt * 3 + py) * 44 + (x + px);
    }
    const bf16* wbase = wc2 + ((long)(par * 64) << 9);
    const int wm0 = tid >> 3, wk0 = (tid & 7) * 8;
    const int wm1 = (tid + 256) >> 3, wk1 = ((tid + 256) & 7) * 8;
    for (int u = tid; u < 1760; u += 256) {
        int rc = u >> 3, c8 = (u & 7) * 8;
        int gy = nt * 3 - 1 + rc / 44, gx = (rc % 44) - 1;
        uint4 v = {0, 0, 0, 0};
        if (gy >= 0 && gy < 42 && gx >= 0 && gx < 42)
            v = *(const uint4*)&d1c[((long)z * 1764 + gy * 42 + gx) * 128 + c8];
        *(uint4*)&H_s[rc * 72 + c8] = v;
    }
    *(uint4*)&W_s[0][wm0 * 72 + wk0] = *(const uint4*)&wbase[wm0 * 512 + wk0];
    *(uint4*)&W_s[0][wm1 * 72 + wk1] = *(const uint4*)&wbase[wm1 * 512 + wk1];
    __syncthreads();
    f32x4 acc[2][4];
    #pragma unroll
    for (int pg = 0; pg < 2; ++pg)
        #pragma unroll
        for (int f = 0; f < 4; ++f) acc[pg][f] = (f32x4){0.f, 0.f, 0.f, 0.f};
    for (int it = 0; it < 8; ++it) {
        const int cc = it >> 2, tap = it & 3;
        const bool ld = (it + 1 < 8);
        uint4 wr0, wr1;
        if (ld) {
            const int ncc = (it + 1) >> 2, ntap = (it + 1) & 3;
            const bf16* src = wbase + ntap * 128 + ncc * 64;
            wr0 = *(const uint4*)&src[wm0 * 512 + wk0];
            wr1 = *(const uint4*)&src[wm1 * 512 + wk1];
        }
        const int a = tap >> 1, b = tap & 1;
        const short* Wc = W_s[it & 1];
        #pragma unroll
        for (int s = 0; s < 2; ++s) {
            bf16x8 bv0 = *(const bf16x8*)&H_s[(hb[0] + a * 44 + b) * 72 + s * 32 + quad * 8];
            bf16x8 bv1 = *(const bf16x8*)&H_s[(hb[1] + a * 44 + b) * 72 + s * 32 + quad * 8];
            #pragma unroll
            for (int f = 0; f < 4; ++f) {
                bf16x8 af = *(const bf16x8*)&Wc[(f * 16 + nl) * 72 + s * 32 + quad * 8];
                acc[0][f] = __builtin_amdgcn_mfma_f32_16x16x32_bf16(af, bv0, acc[0][f], 0, 0, 0);
                acc[1][f] = __builtin_amdgcn_mfma_f32_16x16x32_bf16(af, bv1, acc[1][f], 0, 0, 0);
            }
        }
        if (ld) {
            short* Wn = W_s[(it + 1) & 1];
            *(uint4*)&Wn[wm0 * 72 + wk0] = wr0;
            *(uint4*)&Wn[wm1 * 72 + wk1] = wr1;
        }
        __syncthreads();
        if (tap == 3 && cc == 0) {
            for (int u = tid; u < 1760; u += 256) {
                int rc = u >> 3, c8 = (u & 7) * 8;
                int gy = nt * 3 - 1 + rc / 44, gx = (rc % 44) - 1;
                uint4 v = {0, 0, 0, 0};
                if (gy >= 0 && gy < 42 && gx >= 0 && gx < 42)
                    v = *(const uint4*)&d1c[((long)z * 1764 + gy * 42 + gx) * 128 + 64 + c8];
                *(uint4*)&H_s[rc * 72 + c8] = v;
            }
            __syncthreads();
        }
    }
    #pragma unroll
    for (int pg = 0; pg < 2; ++pg) {
        float part = 0.f;
        #pragma unroll
        for (int f = 0; f < 4; ++f)
            #pragma unroll
            for (int reg = 0; reg < 4; ++reg) {
                const int oc = f * 16 + quad * 4 + reg;
                part += b2f(w3[oc]) * fmaxf(acc[pg][f][reg] + b2f(bias[oc]), 0.f);
            }
        part += __shfl_xor(part, 16);
        part += __shfl_xor(part, 32);
        if (quad == 0 && val[pg]) {
            const int p = pv[pg];
            const int oy = 2 * (p / 42) + py, ox = 2 * (p % 42) + px;
            const float v = part + b2f(b3[0]);
            const long oi = (long)(c0f + z) * 7056 + oy * 84 + ox;
            if (*flag) ((float*)out)[oi] = v;
            else       ((bf16*)out)[oi]  = f2b(v);
        }
    }
}

extern "C" void kernel_launch(void* const* d_in, const int* in_sizes, int n_in,
                              void* d_out, int out_size, void* d_ws, size_t ws_size,
                              hipStream_t stream)
{
    char* wsb = (char*)d_ws;
    static const long woff[15] = {0, 3456, 3584, 151040, 151296, 741120, 741632,
                                  750848, 1799424, 1801472, 2391296, 2391552,
                                  2539008, 2539136, 2539264};
    const long FLAG_OFF = 2539280;
    const long WC1_OFF = 2539296;
    const long WC2_OFF = 3587872;
    const long WCP_OFF = 3850016;
    const long WC3_OFF = 4898592;
    const long WC2E_OFF = 5488416;
    const long WC1E_OFF = 5635872;
    const long DWT_OFF  = 5639968;
    const long CE = 5649184;
    int* flag = (int*)(wsb + FLAG_OFF);

    k_detect<<<1, 256, 0, stream>>>((const unsigned short*)d_in[0], 8192, flag);
    CanonSrc cs;
    for (int i = 0; i < 15; ++i) cs.s[i] = d_in[i + 1];
    k_canon_all<<<(1269633 + 255) / 256, 256, 0, stream>>>(cs, wsb, 1269633, flag);
    k_prep_all<<<6074, 256, 0, stream>>>(wsb);

    const void* x = d_in[0];
    bf16 *enc_b1 = (bf16*)(wsb + woff[1]),
         *enc_b2 = (bf16*)(wsb + woff[3]), *enc_b3 = (bf16*)(wsb + woff[5]),
         *pw_b   = (bf16*)(wsb + woff[8]),
         *dec_b1 = (bf16*)(wsb + woff[10]),
         *dec_b2 = (bf16*)(wsb + woff[12]), *dec_w3 = (bf16*)(wsb + woff[13]),
         *dec_b3 = (bf16*)(wsb + woff[14]);
    bf16* wc1  = (bf16*)(wsb + WC1_OFF);
    bf16* wc2  = (bf16*)(wsb + WC2_OFF);
    bf16* wcp  = (bf16*)(wsb + WCP_OFF);
    bf16* wc3  = (bf16*)(wsb + WC3_OFF);
    bf16* wc2e = (bf16*)(wsb + WC2E_OFF);
    bf16* wc1e = (bf16*)(wsb + WC1E_OFF);
    bf16* dwt  = (bf16*)(wsb + DWT_OFF);

    bf16*  feats = (bf16*)(wsb + CE);                  // 28,901,376 (t-major)
    bf16*  hs0   = (bf16*)(wsb + CE + 28901376);       //  1,806,336
    float* hbuf  = (float*)(wsb + CE + 30707712);      //  3,612,672
    float* cbuf  = (float*)(wsb + CE + 34320384);      //  3,612,672
    bf16*  d1c   = (bf16*)(wsb + CE + 37933056);       // 14,450,688 (decode)
    bf16*  p1c   = (bf16*)(wsb + CE + 37933056);       // 14,450,688 (encode, 64 fr)
    bf16*  p2c   = (bf16*)(wsb + CE + 28901376);       //  7,225,344 (encode alias)
    bf16*  dwout = (bf16*)(wsb + CE + 52383744);       //  3,612,672 (LSTM)

    for (int f0 = 0; f0 < 128; f0 += 64) {
        k_conv1_mfma<<<dim3(28, 1, 64), 256, 0, stream>>>(x, wc1e, enc_b1, p1c, f0, flag);
        k_conv2_mfma<<<dim3(7, 1, 64), 256, 0, stream>>>(p1c, wc2e, enc_b2, p2c);
        k_conv3_mfma<<<dim3(7, 2, 64), 256, 0, stream>>>(p2c, wc3, enc_b3, feats, f0);
    }
    hipMemsetAsync(hbuf, 0, 2 * 3612672, stream);
    for (int t = 0; t < 16; ++t) {
        bf16* hst = (t == 0) ? hs0 : (feats + (long)(t - 1) * 8 * 112896);
        k_dw_vec<<<882, 256, 0, stream>>>(feats, hbuf, dwt, dwout, t);
        k_pw_mfma<<<dim3(7, 8, 8), 256, 0, stream>>>(dwout, wcp, pw_b, hbuf, cbuf,
                                                     hst, d_out, flag,
                                                     (t == 15) ? 1 : 0);
    }
    for (int c0f = 0; c0f < 128; c0f += 32) {
        k_dec1_mfma<<<dim3(4, 4, 32), 256, 0, stream>>>(feats, hs0, wc1, dec_b1, d1c, c0f);
        k_dec2f_mfma<<<dim3(14, 4, 32), 256, 0, stream>>>(d1c, wc2, dec_b2, dec_w3,
                                                          dec_b3, d_out, c0f, flag);
    }
}